// Round 12
// baseline (395.091 us; speedup 1.0000x reference)
//
#include <hip/hip_runtime.h>
#include <math.h>

// Problem constants (B=4, D=64, H=W=64 -> m=n=4096)
#define BB 4
#define DD 64
#define MM 4096
#define M1 4097
#define NORMC 9.0109133472792788f     // log(8192)
#define CSH 11.0f                     // E = exp(d - CSH), fp8 e4m3 safe range
#define SCLX 1.0e12f                  // X -> fp8 A-operand scale (X ~ 3.7e-13)
#define INVSCLX 1.0e-12f

typedef __attribute__((ext_vector_type(8))) short bf16x8;
typedef __attribute__((ext_vector_type(4))) float f32x4;

__device__ __forceinline__ f32x4 mfma16(bf16x8 a, bf16x8 b, f32x4 c) {
    return __builtin_amdgcn_mfma_f32_16x16x32_bf16(a, b, c, 0, 0, 0);
}
__device__ __forceinline__ unsigned short f2bf(float x) {
    unsigned u = __float_as_uint(x);
    u += 0x7fffu + ((u >> 16) & 1u);
    return (unsigned short)(u >> 16);
}

// ===========================================================================
// prep: transpose feats to [b][p][c] bf16 (hi only)
// ===========================================================================
__global__ void __launch_bounds__(256)
prep_kernel(const float* __restrict__ f0, const float* __restrict__ f1,
            unsigned short* __restrict__ h0, unsigned short* __restrict__ h1) {
    __shared__ float T[64][65];
    const int b = blockIdx.y;
    const int p0 = blockIdx.x * 64;
    const float* src = (blockIdx.z == 0 ? f0 : f1) + (size_t)b * DD * MM;
    unsigned short* dh = (blockIdx.z == 0 ? h0 : h1) + (size_t)b * MM * DD;
    const int tid = threadIdx.x;
#pragma unroll
    for (int l = 0; l < 16; ++l) {
        int idx = l * 256 + tid;
        T[idx >> 6][idx & 63] = src[(idx >> 6) * MM + p0 + (idx & 63)];
    }
    __syncthreads();
    const int p = tid >> 2;
    const int cs = (tid & 3) * 16;
    unsigned hw[8];
#pragma unroll
    for (int k = 0; k < 8; ++k) {
        unsigned short a = f2bf(T[cs + 2 * k][p]);
        unsigned short c = f2bf(T[cs + 2 * k + 1][p]);
        hw[k] = (unsigned)a | ((unsigned)c << 16);
    }
    size_t base = (size_t)(p0 + p) * DD + cs;
    *(uint4*)(dh + base)     = make_uint4(hw[0], hw[1], hw[2], hw[3]);
    *(uint4*)(dh + base + 8) = make_uint4(hw[4], hw[5], hw[6], hw[7]);
}

__global__ void __launch_bounds__(256)
norms_kernel(const float* __restrict__ f0, const float* __restrict__ f1,
             float* __restrict__ n0, float* __restrict__ n1) {
    int t = blockIdx.x * 256 + threadIdx.x;
    if (t >= BB * MM) return;
    int b = t / MM, p = t % MM;
    const float* s0 = f0 + (size_t)b * DD * MM + p;
    const float* s1 = f1 + (size_t)b * DD * MM + p;
    float a = 0.f, c = 0.f;
#pragma unroll 8
    for (int k = 0; k < DD; ++k) {
        float x = s0[(size_t)k * MM]; a = fmaf(x, x, a);
        float y = s1[(size_t)k * MM]; c = fmaf(y, y, c);
    }
    n0[t] = a; n1[t] = c;
}

// ===========================================================================
// EB layout: fp8 MFMA B-fragments. Tile = 32 rows (i) x 16 cols (j).
// EB[((b*128 + ig)*256 + jt)*64 + l] is a uint2 (8 bytes): lane l=(lg,lc),
// byte t holds E[i = ig*32 + 8*lg + t][j = jt*16 + lc].
// ===========================================================================
__global__ void __launch_bounds__(256)
distEB_kernel(const unsigned short* __restrict__ h0, const unsigned short* __restrict__ h1,
              const float* __restrict__ n0, const float* __restrict__ n1,
              uint2* __restrict__ EB) {
    __shared__ unsigned char sc[4][640];       // per-wave transpose scratch (stride 40)
    const int id = blockIdx.x;
    const int xcd = id & 7, slot = id >> 3;
    const int b = xcd >> 1;
    const int x = slot * 2 + (xcd & 1);        // 0..127
    const int r0 = x * 32;
    const int tid = threadIdx.x;
    const int w = tid >> 6, l = tid & 63, lg = l >> 4, lc = l & 15;
    const size_t fb = (size_t)b * MM * DD;

    bf16x8 Ah[2][2];
    float n0r[2][4];
#pragma unroll
    for (int st = 0; st < 2; ++st) {
        const unsigned short* pa = h0 + fb + (size_t)(r0 + st * 16 + lc) * DD + 8 * lg;
        Ah[st][0] = *(const bf16x8*)pa; Ah[st][1] = *(const bf16x8*)(pa + 32);
#pragma unroll
        for (int e = 0; e < 4; ++e)
            n0r[st][e] = n0[b * MM + r0 + st * 16 + 4 * lg + e];
    }

    for (int tt = 0; tt < 64; ++tt) {
        const int jt = w * 64 + tt;
        const int j0 = jt * 16;
        const unsigned short* pb = h1 + fb + (size_t)(j0 + lc) * DD + 8 * lg;
        bf16x8 Bh0 = *(const bf16x8*)pb, Bh1 = *(const bf16x8*)(pb + 32);
        float n1j = n1[b * MM + j0 + lc];
        unsigned pk[2];
#pragma unroll
        for (int st = 0; st < 2; ++st) {
            f32x4 acc = {0.f, 0.f, 0.f, 0.f};
            acc = mfma16(Ah[st][0], Bh0, acc);
            acc = mfma16(Ah[st][1], Bh1, acc);
            float Ev[4];
#pragma unroll
            for (int e = 0; e < 4; ++e) {
                float d2 = fmaxf(__builtin_fmaf(-2.f, acc[e], n0r[st][e] + n1j), 0.f);
                Ev[e] = __expf(sqrtf(d2) - CSH);
            }
            int p = __builtin_amdgcn_cvt_pk_fp8_f32(Ev[0], Ev[1], 0, false);
            p = __builtin_amdgcn_cvt_pk_fp8_f32(Ev[2], Ev[3], p, true);
            pk[st] = (unsigned)p;
        }
        *(unsigned*)&sc[w][lc * 40 + 4 * lg]      = pk[0];
        *(unsigned*)&sc[w][lc * 40 + 16 + 4 * lg] = pk[1];
        uint2 v = *(const uint2*)&sc[w][lc * 40 + 8 * lg];
        EB[(((size_t)(b * 128 + x)) * 256 + jt) * 64 + l] = v;
    }
}

// ===========================================================================
// Fused Sinkhorn iteration k (k = 1..10):
//  - materialize W^{k-1} in LDS from csPrev (atomic colsums of iter k-1)
//  - row phase -> X^k (VALU+fp8 decode);  col phase -> atomicAdd csCur
//  - scalar chain: xmm[k] = HB/(sumW^{k-1} + W_MM^{k-1}); sxp[k][b][x] partials
// ===========================================================================
__global__ void __launch_bounds__(512)
sinkF_kernel(const uint2* __restrict__ EB,
             const float* __restrict__ csPrev, float* __restrict__ csCur,
             const float* __restrict__ sxpPrev, float* __restrict__ sxpCur,
             const float* __restrict__ xmmPrev, float* __restrict__ xmmCur,
             float* __restrict__ X, const float* __restrict__ bin, int first) {
    __shared__ float Wl[4096];
    __shared__ float ps[256];
    __shared__ float XL[32];
    __shared__ float sh[8];
    __shared__ float shWMM;
    const int bid = blockIdx.x;                // 0..511
    const int b = bid >> 7, x = bid & 127;
    const int tid = threadIdx.x;
    const int w = tid >> 6, l = tid & 63, lg = l >> 4, lc = l & 15;
    const float bs = *bin;
    const float KC = __expf(-NORMC - CSH);
    const float EBt = __expf(bs - CSH);
    const float HB = 0.5f * __expf(-bs);

    // ---- phase 0: materialize W^{k-1} + scalars ----
    if (first) {
#pragma unroll
        for (int k = 0; k < 8; ++k) Wl[k * 512 + tid] = 1.0f;
        if (tid == 0) shWMM = 1.0f;
        if (l == 0) sh[w] = 512.f * 8.f / 8.f;   // 512 per wave -> 4096 total
    } else {
        const float xmmP = xmmPrev[b];
        if (tid < 64) {                           // W_MM^{k-1}
            float s = sxpPrev[b * 128 + tid] + sxpPrev[b * 128 + 64 + tid];
#pragma unroll
            for (int off = 1; off < 64; off <<= 1) s += __shfl_xor(s, off);
            if (tid == 0) shWMM = HB / (s + xmmP);
        }
        const float db = EBt * xmmP;
        float local = 0.f;
#pragma unroll
        for (int k = 0; k < 8; ++k) {
            float cs = csPrev[b * MM + k * 512 + tid];
            float wv = KC / fmaf(cs, INVSCLX, db);
            Wl[k * 512 + tid] = wv;
            local += wv;
        }
#pragma unroll
        for (int off = 1; off < 64; off <<= 1) local += __shfl_xor(local, off);
        if (l == 0) sh[w] = local;
    }
    __syncthreads();
    const float wMMprev = shWMM;
    const float wmmRow = EBt * wMMprev;
    if (x == 0 && tid == 0) {
        float sumW = ((sh[0] + sh[1]) + (sh[2] + sh[3]))
                   + ((sh[4] + sh[5]) + (sh[6] + sh[7]));
        xmmCur[b] = HB / (sumW + wMMprev);
    }

    // ---- load this block's EB row-slice (32 rows x 4096 cols) ----
    const uint2* EP = EB + (((size_t)(b * 128 + x)) * 256 + w * 32) * 64 + l;
    uint2 ec[32];
#pragma unroll
    for (int k = 0; k < 32; ++k) ec[k] = EP[(size_t)k * 64];

    // ---- row phase ----
    float rs[8] = {};
#pragma unroll
    for (int k = 0; k < 32; ++k) {
        float wv = Wl[(w * 32 + k) * 16 + lc];
        auto p0 = __builtin_amdgcn_cvt_pk_f32_fp8((int)ec[k].x, false);
        auto p1 = __builtin_amdgcn_cvt_pk_f32_fp8((int)ec[k].x, true);
        auto p2 = __builtin_amdgcn_cvt_pk_f32_fp8((int)ec[k].y, false);
        auto p3 = __builtin_amdgcn_cvt_pk_f32_fp8((int)ec[k].y, true);
        rs[0] = fmaf(p0[0], wv, rs[0]); rs[1] = fmaf(p0[1], wv, rs[1]);
        rs[2] = fmaf(p1[0], wv, rs[2]); rs[3] = fmaf(p1[1], wv, rs[3]);
        rs[4] = fmaf(p2[0], wv, rs[4]); rs[5] = fmaf(p2[1], wv, rs[5]);
        rs[6] = fmaf(p3[0], wv, rs[6]); rs[7] = fmaf(p3[1], wv, rs[7]);
    }
#pragma unroll
    for (int off = 1; off < 16; off <<= 1)
#pragma unroll
        for (int t = 0; t < 8; ++t) rs[t] += __shfl_xor(rs[t], off);
    if (lc == 0) {
#pragma unroll
        for (int t = 0; t < 8; ++t) ps[w * 32 + 8 * lg + t] = rs[t];
    }
    __syncthreads();
    if (tid < 32) {
        float s = 0.f;
#pragma unroll
        for (int k = 0; k < 8; ++k) s += ps[k * 32 + tid];
        float xv = KC / (s + wmmRow);
        X[b * MM + x * 32 + tid] = xv;
        XL[tid] = xv * SCLX;
        float t = xv;
#pragma unroll
        for (int off = 1; off < 32; off <<= 1) t += __shfl_xor(t, off);
        if (tid == 0) sxpCur[b * 128 + x] = t;
    }
    __syncthreads();

    // ---- col phase: fp8 MFMA, atomic accumulate column sums ----
    float f0 = XL[8 * lg + 0], f1 = XL[8 * lg + 1];
    float f2 = XL[8 * lg + 2], f3 = XL[8 * lg + 3];
    float f4 = XL[8 * lg + 4], f5 = XL[8 * lg + 5];
    float f6 = XL[8 * lg + 6], f7 = XL[8 * lg + 7];
    int u0 = __builtin_amdgcn_cvt_pk_fp8_f32(f0, f1, 0, false);
    u0 = __builtin_amdgcn_cvt_pk_fp8_f32(f2, f3, u0, true);
    int u1 = __builtin_amdgcn_cvt_pk_fp8_f32(f4, f5, 0, false);
    u1 = __builtin_amdgcn_cvt_pk_fp8_f32(f6, f7, u1, true);
    long long av = (long long)(((unsigned long long)(unsigned)u1 << 32) | (unsigned)u0);
    const f32x4 zero = {0.f, 0.f, 0.f, 0.f};
#pragma unroll
    for (int k = 0; k < 32; ++k) {
        long long bv = (long long)(((unsigned long long)ec[k].y << 32) | ec[k].x);
        f32x4 c = __builtin_amdgcn_mfma_f32_16x16x32_fp8_fp8(av, bv, zero, 0, 0, 0);
        if (l < 16) atomicAdd(&csCur[b * MM + (w * 32 + k) * 16 + l], c[0]);
    }
}

// ===========================================================================
// gamma: main blocks (0..511, from EB) + edge blocks (bid>=512)
// W^10 materialized from cs10 + xmm10; W_MM^10 from sxp10.
// ===========================================================================
__global__ void __launch_bounds__(256)
finF_kernel(const uint2* __restrict__ EB, const float* __restrict__ X,
            const float* __restrict__ cs10, const float* __restrict__ sxp10,
            const float* __restrict__ xmm10, const float* __restrict__ bin,
            float* __restrict__ G, float* __restrict__ pA, float* __restrict__ pB) {
    const int bid = blockIdx.x;
    const int tid = threadIdx.x;
    const float bs = *bin;
    const float KC = __expf(-NORMC - CSH);
    const float EBt = __expf(bs - CSH);
    const float HB = 0.5f * __expf(-bs);
    if (bid >= BB * 128) {
        // ---- edge path ----
        __shared__ float wmm10s[4];
        if (tid < 256) {
            int bb = tid >> 6, ll = tid & 63;
            float s = sxp10[bb * 128 + ll] + sxp10[bb * 128 + 64 + ll];
#pragma unroll
            for (int off = 1; off < 64; off <<= 1) s += __shfl_xor(s, off);
            if (ll == 0) wmm10s[bb] = HB / (s + xmm10[bb]);
        }
        __syncthreads();
        const int eb = bid - BB * 128;
        const float CC = __expf(NORMC + bs);
        int t = eb * 256 + tid;
        float pc = 0.f, pr = 0.f;
        if (t < BB * M1) {
            int b = t / M1, j = t % M1;
            float wj = (j < MM) ? KC / fmaf(cs10[b * MM + j], INVSCLX, EBt * xmm10[b])
                                : wmm10s[b];
            float g = CC * xmm10[b] * wj;              // dustbin row
            G[((size_t)b * M1 + MM) * M1 + j] = g;
            if (j == MM) pc += g;
        } else if (t < BB * M1 + BB * MM) {
            int q = t - BB * M1;
            int b = q / MM, i = q % MM;
            float g = CC * X[b * MM + i] * wmm10s[b];  // dustbin col
            G[((size_t)b * M1 + i) * M1 + MM] = g;
            pc += g; pr += g;
        }
#pragma unroll
        for (int off = 1; off < 64; off <<= 1) {
            pc += __shfl_xor(pc, off);
            pr += __shfl_xor(pr, off);
        }
        __shared__ float e0[4], e1[4];
        if ((tid & 63) == 0) { e0[tid >> 6] = pc; e1[tid >> 6] = pr; }
        __syncthreads();
        if (tid == 0) {
            pB[eb * 2 + 0] = e0[0] + e0[1] + e0[2] + e0[3];
            pB[eb * 2 + 1] = e1[0] + e1[1] + e1[2] + e1[3];
        }
        return;
    }
    __shared__ float T[256][36];
    __shared__ float Wl[4096];
    __shared__ float XL[32];
    const int b = bid >> 7, x = bid & 127;
    const int w = tid >> 6, l = tid & 63, lg = l >> 4, lc = l & 15;
    {
        const float db = EBt * xmm10[b];
#pragma unroll
        for (int k = 0; k < 16; ++k) {
            float cs = cs10[b * MM + k * 256 + tid];
            Wl[k * 256 + tid] = KC / fmaf(cs, INVSCLX, db);
        }
    }
    if (tid < 32) XL[tid] = X[b * MM + x * 32 + tid] * __expf(NORMC + CSH);
    __syncthreads();

    const uint2* EBb = EB + ((size_t)(b * 128 + x)) * 256 * 64;
    float pm = 0.f, pr = 0.f;
    for (int ch = 0; ch < 16; ++ch) {
#pragma unroll
        for (int q = 0; q < 4; ++q) {
            const int jt = ch * 16 + w * 4 + q;
            uint2 ev = EBb[(size_t)jt * 64 + l];
            float wv = Wl[jt * 16 + lc];
            auto p0 = __builtin_amdgcn_cvt_pk_f32_fp8((int)ev.x, false);
            auto p1 = __builtin_amdgcn_cvt_pk_f32_fp8((int)ev.x, true);
            auto p2 = __builtin_amdgcn_cvt_pk_f32_fp8((int)ev.y, false);
            auto p3 = __builtin_amdgcn_cvt_pk_f32_fp8((int)ev.y, true);
            float Ef[8] = {p0[0], p0[1], p1[0], p1[1], p2[0], p2[1], p3[0], p3[1]};
            float g[8];
#pragma unroll
            for (int t = 0; t < 8; ++t) {
                g[t] = Ef[t] * XL[8 * lg + t] * wv;
                pm = fmaf(g[t], (Ef[t] > 0.f) ? (CSH + __logf(Ef[t])) : 0.f, pm);
                pr += g[t];
            }
            const int jl = (w * 4 + q) * 16 + lc;
            f32x4 v0 = {g[0], g[1], g[2], g[3]};
            f32x4 v1 = {g[4], g[5], g[6], g[7]};
            *(f32x4*)&T[jl][8 * lg]     = v0;
            *(f32x4*)&T[jl][8 * lg + 4] = v1;
        }
        __syncthreads();
        float* gb = G + ((size_t)(b * M1 + x * 32)) * M1 + ch * 256 + tid;
#pragma unroll
        for (int r = 0; r < 32; ++r) gb[(size_t)r * M1] = T[tid][r];
        __syncthreads();
    }
#pragma unroll
    for (int off = 1; off < 64; off <<= 1) {
        pm += __shfl_xor(pm, off);
        pr += __shfl_xor(pr, off);
    }
    __shared__ float s0[4], s1[4];
    if (l == 0) { s0[w] = pm; s1[w] = pr; }
    __syncthreads();
    if (tid == 0) {
        pA[bid * 2 + 0] = s0[0] + s0[1] + s0[2] + s0[3];
        pA[bid * 2 + 1] = s1[0] + s1[1] + s1[2] + s1[3];
    }
}

__global__ void __launch_bounds__(256)
reduce_out_kernel(const float* __restrict__ pA, int nA,
                  const float* __restrict__ pB, int nB, float* __restrict__ out) {
    const int tid = threadIdx.x;
    float pm = 0.f, prA = 0.f, pc = 0.f, prB = 0.f;
    for (int r = tid; r < nA; r += 256) { pm += pA[2 * r]; prA += pA[2 * r + 1]; }
    for (int r = tid; r < nB; r += 256) { pc += pB[2 * r]; prB += pB[2 * r + 1]; }
#pragma unroll
    for (int off = 1; off < 64; off <<= 1) {
        pm += __shfl_xor(pm, off);
        prA += __shfl_xor(prA, off);
        pc += __shfl_xor(pc, off);
        prB += __shfl_xor(prB, off);
    }
    __shared__ float a0[4], a1[4], a2[4], a3[4];
    if ((tid & 63) == 0) {
        int w = tid >> 6;
        a0[w] = pm; a1[w] = prA; a2[w] = pc; a3[w] = prB;
    }
    __syncthreads();
    if (tid == 0) {
        float PM = a0[0] + a0[1] + a0[2] + a0[3];
        float PRA = a1[0] + a1[1] + a1[2] + a1[3];
        float PC = a2[0] + a2[1] + a2[2] + a2[3];
        float PRB = a3[0] + a3[1] + a3[2] + a3[3];
        out[0] = PM / (4.0f * 4096.0f);
        out[1] = PC / (4.0f * 4097.0f) + (PRA + PRB) / (4.0f * 4096.0f * 4097.0f);
    }
}

// ===========================================================================
extern "C" void kernel_launch(void* const* d_in, const int* in_sizes, int n_in,
                              void* d_out, int out_size, void* d_ws, size_t ws_size,
                              hipStream_t stream) {
    const float* feat0 = (const float*)d_in[0];
    const float* feat1 = (const float*)d_in[1];
    const float* bin   = (const float*)d_in[2];
    float* out = (float*)d_out;
    float* G   = out + 2;                      // gamma region [4][4097][4097]
    float* ws  = (float*)d_ws;

    // ws layout (float offsets), ~72 MB total
    const size_t OF_X   = 0;                   // 16384
    const size_t OF_XMM = 16384;               // 11*4 (pad 64)
    const size_t OF_SXP = 16448;               // 11*512 = 5632
    const size_t OF_CS  = 22080;               // 11*16384 = 180224
    const size_t OF_PA  = 202304;              // 1024
    const size_t OF_PB  = 203328;              // 288
    const size_t OF_N0  = 203616;              // 16384
    const size_t OF_N1  = 220000;              // 16384
    const size_t OF_BF  = 236384;              // 2 x 1M ushorts = 1048576 floats
    const size_t OF_E8  = 1284960;             // EB: 64MB = 16777216 floats

    float* X   = ws + OF_X;
    float* XMM = ws + OF_XMM;
    float* SXP = ws + OF_SXP;
    float* CS  = ws + OF_CS;
    float* pA  = ws + OF_PA;
    float* pB  = ws + OF_PB;
    float* n0  = ws + OF_N0;
    float* n1  = ws + OF_N1;
    unsigned short* h0 = (unsigned short*)(ws + OF_BF);
    unsigned short* h1 = h0 + 1048576;
    uint2* EB = (uint2*)(ws + OF_E8);

    // zero all atomic colsum buffers once per launch
    hipMemsetAsync(CS, 0, 11 * 16384 * sizeof(float), stream);
    prep_kernel<<<dim3(64, BB, 2), 256, 0, stream>>>(feat0, feat1, h0, h1);
    norms_kernel<<<64, 256, 0, stream>>>(feat0, feat1, n0, n1);
    distEB_kernel<<<512, 256, 0, stream>>>(h0, h1, n0, n1, EB);
    for (int k = 1; k <= 10; ++k) {
        sinkF_kernel<<<512, 512, 0, stream>>>(
            EB,
            CS + (size_t)(k - 1) * 16384, CS + (size_t)k * 16384,
            SXP + (size_t)(k - 1) * 512,  SXP + (size_t)k * 512,
            XMM + (size_t)(k - 1) * 4,    XMM + (size_t)k * 4,
            X, bin, (k == 1) ? 1 : 0);
    }
    finF_kernel<<<BB * 128 + 129, 256, 0, stream>>>(
        EB, X, CS + 10 * 16384, SXP + 10 * 512, XMM + 10 * 4, bin, G, pA, pB);
    reduce_out_kernel<<<1, 256, 0, stream>>>(pA, BB * 128, pB, 129, out);
}